// Round 2
// baseline (699.226 us; speedup 1.0000x reference)
//
#include <hip/hip_runtime.h>

// ---------------- common types/helpers ----------------
typedef float fx4 __attribute__((ext_vector_type(4)));
typedef short s16x4 __attribute__((ext_vector_type(4)));
typedef short s16x8 __attribute__((ext_vector_type(8)));
typedef __bf16 bf16x8 __attribute__((ext_vector_type(8)));

__device__ __forceinline__ short f2bf(float f) {
  unsigned u = __builtin_bit_cast(unsigned, f);
  u += 0x7fffu + ((u >> 16) & 1u);   // RNE
  return (short)(u >> 16);
}

__device__ __forceinline__ bf16x8 ld8(const short* p) {
  s16x8 v = *(const s16x8*)p;
  return __builtin_bit_cast(bf16x8, v);
}

// ---------------- GEMM: C[M,N] = A[M,K] @ B[K,N] ----------------
// A: f32 (ABF=false) or bf16/short (ABF=true). B: f32 [K,N] row-major.
// 128x128 tile, BK=32, 4 waves (2x2), each wave 4x4 16x16x32 mfma frags.
#define LDA 40
#define LDB 40

template<bool ABF>
__global__ __launch_bounds__(256) void gemm_k(const void* __restrict__ Ap,
    const float* __restrict__ Bp, float* __restrict__ Cp, int N, int K) {
  __shared__ short As[128 * LDA];
  __shared__ short Bs[128 * LDB];
  const int tiles_n = N >> 7;
  const int tm = blockIdx.x / tiles_n, tn = blockIdx.x % tiles_n;
  const int tid = threadIdx.x;
  const int lane = tid & 63, wv = tid >> 6;
  const int wr = (wv >> 1) << 6, wc = (wv & 1) << 6;
  const int r0 = tm << 7, c0 = tn << 7;
  const int lrow = lane & 15, lk = (lane >> 4) << 3;
  const int bn4 = tid & 31, bk4 = tid >> 5;
  fx4 acc[4][4] = {};

  for (int k0 = 0; k0 < K; k0 += 32) {
    // ---- stage A (128 x 32) ----
    if (ABF) {
      const short* A = (const short*)Ap;
      #pragma unroll
      for (int i = 0; i < 2; ++i) {
        int idx = i * 256 + tid;
        int row = idx >> 2, c8 = (idx & 3) << 3;
        *(s16x8*)&As[row * LDA + c8] =
            *(const s16x8*)(A + (size_t)(r0 + row) * K + k0 + c8);
      }
    } else {
      const float* A = (const float*)Ap;
      #pragma unroll
      for (int i = 0; i < 4; ++i) {
        int idx = i * 256 + tid;
        int row = idx >> 3, c4 = (idx & 7) << 2;
        fx4 v = *(const fx4*)(A + (size_t)(r0 + row) * K + k0 + c4);
        s16x4 w;
        w[0] = f2bf(v[0]); w[1] = f2bf(v[1]); w[2] = f2bf(v[2]); w[3] = f2bf(v[3]);
        *(s16x4*)&As[row * LDA + c4] = w;
      }
    }
    // ---- stage B transposed (Bs[n][k]) with XOR k-swizzle ----
    {
      fx4 v0 = *(const fx4*)(Bp + (size_t)(k0 + bk4 * 4 + 0) * N + c0 + bn4 * 4);
      fx4 v1 = *(const fx4*)(Bp + (size_t)(k0 + bk4 * 4 + 1) * N + c0 + bn4 * 4);
      fx4 v2 = *(const fx4*)(Bp + (size_t)(k0 + bk4 * 4 + 2) * N + c0 + bn4 * 4);
      fx4 v3 = *(const fx4*)(Bp + (size_t)(k0 + bk4 * 4 + 3) * N + c0 + bn4 * 4);
      #pragma unroll
      for (int j = 0; j < 4; ++j) {
        int nn = bn4 * 4 + j;
        int ks = (bk4 * 4) ^ (((nn >> 2) & 3) << 3);
        s16x4 w;
        w[0] = f2bf(v0[j]); w[1] = f2bf(v1[j]); w[2] = f2bf(v2[j]); w[3] = f2bf(v3[j]);
        *(s16x4*)&Bs[nn * LDB + ks] = w;
      }
    }
    __syncthreads();
    // ---- fragments + MFMA ----
    bf16x8 af[4], bfr[4];
    #pragma unroll
    for (int m = 0; m < 4; ++m)
      af[m] = ld8(&As[(wr + m * 16 + lrow) * LDA + lk]);
    #pragma unroll
    for (int n = 0; n < 4; ++n) {
      int nn = wc + n * 16 + lrow;
      bfr[n] = ld8(&Bs[nn * LDB + (lk ^ (((nn >> 2) & 3) << 3))]);
    }
    #pragma unroll
    for (int m = 0; m < 4; ++m)
      #pragma unroll
      for (int n = 0; n < 4; ++n)
        acc[m][n] = __builtin_amdgcn_mfma_f32_16x16x32_bf16(af[m], bfr[n], acc[m][n], 0, 0, 0);
    __syncthreads();
  }
  // ---- epilogue: C layout col=lane&15, row=(lane>>4)*4+j ----
  const int g4 = (lane >> 4) << 2;
  #pragma unroll
  for (int m = 0; m < 4; ++m)
    #pragma unroll
    for (int n = 0; n < 4; ++n)
      #pragma unroll
      for (int j = 0; j < 4; ++j) {
        int row = r0 + wr + m * 16 + g4 + j;
        int col = c0 + wc + n * 16 + lrow;
        Cp[(size_t)row * N + col] = acc[m][n][j];
      }
}

// ---------------- RMSNorm + RoPE + KV scatter ----------------
// one wave per (token, head) row; lane l holds d=l and d=l+64 (rotate-half pairs)
__global__ __launch_bounds__(256) void nr_k(const float* __restrict__ xq,
    const float* __restrict__ xkv, const float* __restrict__ qnw,
    const float* __restrict__ knw, const float* __restrict__ cosb,
    const float* __restrict__ sinb, const int* __restrict__ idx,
    short* __restrict__ qb, short* __restrict__ kbp, short* __restrict__ vbp,
    float* __restrict__ bufo) {
  int rid = blockIdx.x * 4 + (threadIdx.x >> 6);
  int l = threadIdx.x & 63;
  int type, t, h;
  if (rid < 65536)      { type = 0; t = rid >> 5; h = rid & 31; }
  else if (rid < 81920) { type = 1; int r = rid - 65536; t = r >> 3; h = r & 7; }
  else                  { type = 2; int r = rid - 81920; t = r >> 3; h = r & 7; }
  int s = t & 1023;
  const float* src = (type == 0) ? xq + (size_t)t * 4096 + h * 128
                   : (type == 1) ? xkv + (size_t)t * 2048 + h * 128
                                 : xkv + (size_t)t * 2048 + 1024 + h * 128;
  float e0 = src[l], e1 = src[l + 64];
  float out0, out1;
  if (type < 2) {
    float ss = e0 * e0 + e1 * e1;
    #pragma unroll
    for (int off = 1; off < 64; off <<= 1) ss += __shfl_xor(ss, off);
    float r = rsqrtf(ss * (1.0f / 128.0f) + 1e-6f);
    const float* nw = (type == 0) ? qnw : knw;
    float n0 = e0 * r * nw[l], n1 = e1 * r * nw[l + 64];
    float c0 = cosb[s * 128 + l], c1 = cosb[s * 128 + 64 + l];
    float s0 = sinb[s * 128 + l], s1 = sinb[s * 128 + 64 + l];
    out0 = n0 * c0 - n1 * s0;
    out1 = n1 * c1 + n0 * s1;
  } else { out0 = e0; out1 = e1; }
  if (type == 0) {
    short* d = qb + (size_t)t * 4096 + h * 128;
    d[l] = f2bf(out0); d[l + 64] = f2bf(out1);
  } else {
    int br = idx[t];
    float* bd = bufo + (size_t)br * 2048 + (type == 1 ? 0 : 1024) + h * 128;
    bd[l] = out0; bd[l + 64] = out1;
    short* d = (type == 1) ? kbp + (size_t)t * 1024 + h * 128
                           : vbp + (size_t)t * 1024 + h * 128;
    d[l] = f2bf(out0); d[l + 64] = f2bf(out1);
  }
}

// ---------------- causal GQA flash attention ----------------
// block = (b, h, 64-q-row tile), 4 waves of 16 q rows each, KV tiles of 64
#define KLD 136
#define VLD 72
#define PLD 72

__global__ __launch_bounds__(256) void attn_k(const short* __restrict__ qb,
    const short* __restrict__ kbp, const short* __restrict__ vbp,
    short* __restrict__ ob) {
  __shared__ short Ks[64 * KLD];
  __shared__ short Vs[128 * VLD];
  __shared__ short Ps[4][16 * PLD];
  const int bid = blockIdx.x;
  const int qt = bid & 15, h = (bid >> 4) & 31, b = bid >> 9;
  const int kvh = h >> 2;
  const int tid = threadIdx.x, lane = tid & 63, w = tid >> 6;
  const int lrow = lane & 15, lg = lane >> 4, lk = lg << 3;
  const int q0 = qt << 6;
  const float SC2 = 0.088388347648318447f * 1.4426950408889634f; // scale*log2(e)

  bf16x8 qf[4];
  {
    const short* qp = qb + ((size_t)(b * 1024 + q0 + w * 16 + lrow) * 32 + h) * 128 + lk;
    #pragma unroll
    for (int kb4 = 0; kb4 < 4; ++kb4) qf[kb4] = ld8(qp + kb4 * 32);
  }
  float m[4], lsum[4];
  fx4 acc[8] = {};
  #pragma unroll
  for (int j = 0; j < 4; ++j) { m[j] = -3.0e38f; lsum[j] = 0.f; }

  for (int kt = 0; kt <= qt; ++kt) {
    const int kv0 = kt << 6;
    // stage K row-major + V transposed (XOR-swizzled kv index)
    #pragma unroll
    for (int it = 0; it < 4; ++it) {
      int idx = it * 256 + tid;
      int r = idx >> 4, d8 = (idx & 15) << 3;
      size_t base = ((size_t)(b * 1024 + kv0 + r) * 8 + kvh) * 128 + d8;
      *(s16x8*)&Ks[r * KLD + d8] = *(const s16x8*)(kbp + base);
      s16x8 vv = *(const s16x8*)(vbp + base);
      int swz = ((d8 >> 3) & 7) << 3;
      #pragma unroll
      for (int j = 0; j < 8; ++j)
        Vs[(d8 + j) * VLD + (r ^ swz)] = vv[j];
    }
    __syncthreads();
    // S = Q K^T (16x64 per wave)
    fx4 sf[4];
    #pragma unroll
    for (int nc = 0; nc < 4; ++nc) {
      fx4 z = {0.f, 0.f, 0.f, 0.f};
      sf[nc] = z;
      #pragma unroll
      for (int kb4 = 0; kb4 < 4; ++kb4) {
        bf16x8 kf = ld8(&Ks[(nc * 16 + lrow) * KLD + kb4 * 32 + lk]);
        sf[nc] = __builtin_amdgcn_mfma_f32_16x16x32_bf16(qf[kb4], kf, sf[nc], 0, 0, 0);
      }
    }
    // causal mask on the diagonal tile
    if (kt == qt) {
      #pragma unroll
      for (int nc = 0; nc < 4; ++nc)
        #pragma unroll
        for (int j = 0; j < 4; ++j) {
          int qr = q0 + w * 16 + (lg << 2) + j;
          int kc = kv0 + nc * 16 + lrow;
          if (kc > qr) sf[nc][j] = -3.0e38f;
        }
    }
    // online softmax (rows live in lanes sharing lg; reduce over low 4 lane bits)
    float pm[4];
    #pragma unroll
    for (int j = 0; j < 4; ++j) pm[j] = -3.0e38f;
    #pragma unroll
    for (int nc = 0; nc < 4; ++nc)
      #pragma unroll
      for (int j = 0; j < 4; ++j) pm[j] = fmaxf(pm[j], sf[nc][j]);
    #pragma unroll
    for (int j = 0; j < 4; ++j) {
      pm[j] = fmaxf(pm[j], __shfl_xor(pm[j], 1));
      pm[j] = fmaxf(pm[j], __shfl_xor(pm[j], 2));
      pm[j] = fmaxf(pm[j], __shfl_xor(pm[j], 4));
      pm[j] = fmaxf(pm[j], __shfl_xor(pm[j], 8));
    }
    float alpha[4], rs[4];
    #pragma unroll
    for (int j = 0; j < 4; ++j) {
      float mn = fmaxf(m[j], pm[j]);
      alpha[j] = exp2f((m[j] - mn) * SC2);
      m[j] = mn;
      rs[j] = 0.f;
    }
    #pragma unroll
    for (int nc = 0; nc < 4; ++nc)
      #pragma unroll
      for (int j = 0; j < 4; ++j) {
        float p = exp2f((sf[nc][j] - m[j]) * SC2);
        rs[j] += p;
        Ps[w][((lg << 2) + j) * PLD + nc * 16 + lrow] = f2bf(p);
      }
    #pragma unroll
    for (int j = 0; j < 4; ++j) {
      rs[j] += __shfl_xor(rs[j], 1);
      rs[j] += __shfl_xor(rs[j], 2);
      rs[j] += __shfl_xor(rs[j], 4);
      rs[j] += __shfl_xor(rs[j], 8);
      lsum[j] = lsum[j] * alpha[j] + rs[j];
    }
    #pragma unroll
    for (int dg = 0; dg < 8; ++dg)
      #pragma unroll
      for (int j = 0; j < 4; ++j) acc[dg][j] *= alpha[j];
    // PV
    #pragma unroll
    for (int kb2 = 0; kb2 < 2; ++kb2) {
      bf16x8 pf = ld8(&Ps[w][lrow * PLD + kb2 * 32 + lk]);
      #pragma unroll
      for (int dg = 0; dg < 8; ++dg) {
        int d = dg * 16 + lrow;
        int kvs = (kb2 * 32 + lk) ^ (((d >> 3) & 7) << 3);
        bf16x8 vf = ld8(&Vs[d * VLD + kvs]);
        acc[dg] = __builtin_amdgcn_mfma_f32_16x16x32_bf16(pf, vf, acc[dg], 0, 0, 0);
      }
    }
    __syncthreads();
  }
  // epilogue
  #pragma unroll
  for (int j = 0; j < 4; ++j) {
    float rl = 1.0f / lsum[j];
    int t = b * 1024 + q0 + w * 16 + (lg << 2) + j;
    short* op = ob + ((size_t)t * 32 + h) * 128;
    #pragma unroll
    for (int dg = 0; dg < 8; ++dg)
      op[dg * 16 + lrow] = f2bf(acc[dg][j] * rl);
  }
}

// ---------------- launcher ----------------
extern "C" void kernel_launch(void* const* d_in, const int* in_sizes, int n_in,
                              void* d_out, int out_size, void* d_ws, size_t ws_size,
                              hipStream_t stream) {
  (void)in_sizes; (void)n_in; (void)out_size; (void)ws_size;
  const float* x    = (const float*)d_in[0];
  const float* qw   = (const float*)d_in[1];
  const float* kvw  = (const float*)d_in[2];
  const float* ow   = (const float*)d_in[3];
  const float* qnw  = (const float*)d_in[4];
  const float* knw  = (const float*)d_in[5];
  const float* cosb = (const float*)d_in[6];
  const float* sinb = (const float*)d_in[7];
  const float* kvbf = (const float*)d_in[8];
  const int*   idx  = (const int*)d_in[9];

  float* outp = (float*)d_out;
  float* bufp = outp + (size_t)2048 * 4096;

  char* ws = (char*)d_ws;
  size_t off = 0;
  float* xq   = (float*)(ws + off); off += (size_t)2048 * 4096 * 4;
  float* xkv  = (float*)(ws + off); off += (size_t)2048 * 2048 * 4;
  short* qb   = (short*)(ws + off); off += (size_t)2048 * 4096 * 2;
  short* kbp  = (short*)(ws + off); off += (size_t)2048 * 1024 * 2;
  short* vbp  = (short*)(ws + off); off += (size_t)2048 * 1024 * 2;
  short* attnb = (short*)xq;  // reuse (xq dead after nr_k)

  // 1) projections
  gemm_k<false><<<dim3(16 * 32), dim3(256), 0, stream>>>((const void*)x, qw, xq, 4096, 4096);
  gemm_k<false><<<dim3(16 * 16), dim3(256), 0, stream>>>((const void*)x, kvw, xkv, 2048, 4096);
  // 2) kv buffer base copy, then norm/rope/scatter
  hipMemcpyAsync(bufp, kvbf, (size_t)16384 * 2048 * 4, hipMemcpyDeviceToDevice, stream);
  nr_k<<<dim3(98304 / 4), dim3(256), 0, stream>>>(xq, xkv, qnw, knw, cosb, sinb, idx,
                                                  qb, kbp, vbp, bufp);
  // 3) attention
  attn_k<<<dim3(2 * 32 * 16), dim3(256), 0, stream>>>(qb, kbp, vbp, attnb);
  // 4) output projection
  gemm_k<true><<<dim3(16 * 32), dim3(256), 0, stream>>>((const void*)attnb, ow, outp, 4096, 4096);
}

// Round 3
// 610.304 us; speedup vs baseline: 1.1457x; 1.1457x over previous
//
#include <hip/hip_runtime.h>

// ---------------- common types/helpers ----------------
typedef float fx4 __attribute__((ext_vector_type(4)));
typedef short s16x4 __attribute__((ext_vector_type(4)));
typedef short s16x8 __attribute__((ext_vector_type(8)));
typedef __bf16 bf16x8 __attribute__((ext_vector_type(8)));

__device__ __forceinline__ short f2bf(float f) {
  unsigned u = __builtin_bit_cast(unsigned, f);
  u += 0x7fffu + ((u >> 16) & 1u);   // RNE
  return (short)(u >> 16);
}

__device__ __forceinline__ bf16x8 ld8(const short* p) {
  s16x8 v = *(const s16x8*)p;
  return __builtin_bit_cast(bf16x8, v);
}

// async global->LDS, 16B per lane; LDS dest is wave-uniform base + lane*16
__device__ __forceinline__ void gld16(const void* g, void* l) {
  __builtin_amdgcn_global_load_lds(
      (const __attribute__((address_space(1))) unsigned*)g,
      (__attribute__((address_space(3))) unsigned*)l, 16, 0, 0);
}

// ---------------- transpose+convert: out[n][k] = bf16(in[k][n]) ----------------
// in: f32 [K,N] row-major; out: bf16 [N,K]; 64x64 tiles, 256 threads
__global__ __launch_bounds__(256) void tr_k(const float* __restrict__ in,
    short* __restrict__ out, int K, int N) {
  __shared__ short T[64][72];
  const int ktiles = K >> 6;
  const int tk0 = (blockIdx.x % ktiles) << 6;
  const int tn0 = (blockIdx.x / ktiles) << 6;
  const int tid = threadIdx.x;
  #pragma unroll
  for (int i = 0; i < 4; ++i) {
    int idx = i * 256 + tid;
    int k = idx >> 4, n4 = (idx & 15) << 2;
    fx4 v = *(const fx4*)(in + (size_t)(tk0 + k) * N + tn0 + n4);
    #pragma unroll
    for (int j = 0; j < 4; ++j) T[n4 + j][k] = f2bf(v[j]);
  }
  __syncthreads();
  #pragma unroll
  for (int i = 0; i < 2; ++i) {
    int idx = i * 256 + tid;
    int n = idx >> 3, k8 = (idx & 7) << 3;
    *(s16x8*)(out + (size_t)(tn0 + n) * K + tk0 + k8) = *(const s16x8*)&T[n][k8];
  }
}

// ---------------- GEMM: C[M,N] = A[M,K] @ Bt[N,K]^T ----------------
// A: f32 (ABF=false, converted during staging) or bf16 (ABF=true, global_load_lds)
// Bt: bf16 [N,K]. 128x128 tile, BK=32, 4 waves (2x2), 4x4 16x16x32 frags/wave.
// LDS tiles are [128][32] bf16 LINEAR (global_load_lds requirement); bank
// conflicts broken by XOR-swizzling the 16B-chunk index with (row&3) on the
// SOURCE side and applying the same XOR on ds_read (rule: both-sides-or-neither).
template<bool ABF>
__global__ __launch_bounds__(256) void gemm_k(const void* __restrict__ Ap,
    const short* __restrict__ Bt, float* __restrict__ Cp, int N, int K) {
  __shared__ short As[128 * 32];
  __shared__ short Bs[128 * 32];
  const int tiles_n = N >> 7;
  const int tm = blockIdx.x / tiles_n, tn = blockIdx.x % tiles_n;
  const int tid = threadIdx.x;
  const int lane = tid & 63, wv = tid >> 6;
  const int wr = (wv >> 1) << 6, wc = (wv & 1) << 6;
  const int r0 = tm << 7, c0 = tn << 7;
  const int lrow = lane & 15, lg = lane >> 4;
  fx4 acc[4][4] = {};

  for (int k0 = 0; k0 < K; k0 += 32) {
    // ---- stage A (128 x 32) ----
    if (ABF) {
      const short* A = (const short*)Ap;
      #pragma unroll
      for (int i = 0; i < 2; ++i) {
        int c = i * 256 + tid;
        int row = c >> 2, p = c & 3;
        int gk8 = ((p ^ (row & 3)) << 3);
        gld16(A + (size_t)(r0 + row) * K + k0 + gk8, &As[(i * 256 + wv * 64) * 8]);
      }
    } else {
      const float* A = (const float*)Ap;
      #pragma unroll
      for (int i = 0; i < 4; ++i) {
        int idx = i * 256 + tid;
        int row = idx >> 3, q = idx & 7;
        int k16 = q >> 1, h = q & 1;
        int gk = ((k16 ^ (row & 3)) << 3) + (h << 2);
        fx4 v = *(const fx4*)(A + (size_t)(r0 + row) * K + k0 + gk);
        s16x4 w;
        w[0] = f2bf(v[0]); w[1] = f2bf(v[1]); w[2] = f2bf(v[2]); w[3] = f2bf(v[3]);
        *(s16x4*)&As[row * 32 + (k16 << 3) + (h << 2)] = w;
      }
    }
    // ---- stage B (128 x 32) via global_load_lds ----
    #pragma unroll
    for (int i = 0; i < 2; ++i) {
      int c = i * 256 + tid;
      int row = c >> 2, p = c & 3;
      int gk8 = ((p ^ (row & 3)) << 3);
      gld16(Bt + (size_t)(c0 + row) * K + k0 + gk8, &Bs[(i * 256 + wv * 64) * 8]);
    }
    __syncthreads();
    // ---- fragments (swizzled ds_read_b128) + MFMA ----
    bf16x8 af[4], bfr[4];
    #pragma unroll
    for (int m = 0; m < 4; ++m) {
      int row = wr + m * 16 + lrow;
      af[m] = ld8(&As[row * 32 + ((lg ^ (row & 3)) << 3)]);
    }
    #pragma unroll
    for (int n = 0; n < 4; ++n) {
      int row = wc + n * 16 + lrow;
      bfr[n] = ld8(&Bs[row * 32 + ((lg ^ (row & 3)) << 3)]);
    }
    #pragma unroll
    for (int m = 0; m < 4; ++m)
      #pragma unroll
      for (int n = 0; n < 4; ++n)
        acc[m][n] = __builtin_amdgcn_mfma_f32_16x16x32_bf16(af[m], bfr[n], acc[m][n], 0, 0, 0);
    __syncthreads();
  }
  // ---- epilogue: C layout col=lane&15, row=(lane>>4)*4+j ----
  const int g4 = lg << 2;
  #pragma unroll
  for (int m = 0; m < 4; ++m)
    #pragma unroll
    for (int n = 0; n < 4; ++n)
      #pragma unroll
      for (int j = 0; j < 4; ++j) {
        int row = r0 + wr + m * 16 + g4 + j;
        int col = c0 + wc + n * 16 + lrow;
        Cp[(size_t)row * N + col] = acc[m][n][j];
      }
}

// ---------------- RMSNorm + RoPE + KV scatter ----------------
// one wave per (token, head) row; lane l holds d=l and d=l+64 (rotate-half pairs)
__global__ __launch_bounds__(256) void nr_k(const float* __restrict__ xq,
    const float* __restrict__ xkv, const float* __restrict__ qnw,
    const float* __restrict__ knw, const float* __restrict__ cosb,
    const float* __restrict__ sinb, const int* __restrict__ idx,
    short* __restrict__ qb, short* __restrict__ kbp, short* __restrict__ vbp,
    float* __restrict__ bufo) {
  int rid = blockIdx.x * 4 + (threadIdx.x >> 6);
  int l = threadIdx.x & 63;
  int type, t, h;
  if (rid < 65536)      { type = 0; t = rid >> 5; h = rid & 31; }
  else if (rid < 81920) { type = 1; int r = rid - 65536; t = r >> 3; h = r & 7; }
  else                  { type = 2; int r = rid - 81920; t = r >> 3; h = r & 7; }
  int s = t & 1023;
  const float* src = (type == 0) ? xq + (size_t)t * 4096 + h * 128
                   : (type == 1) ? xkv + (size_t)t * 2048 + h * 128
                                 : xkv + (size_t)t * 2048 + 1024 + h * 128;
  float e0 = src[l], e1 = src[l + 64];
  float out0, out1;
  if (type < 2) {
    float ss = e0 * e0 + e1 * e1;
    #pragma unroll
    for (int off = 1; off < 64; off <<= 1) ss += __shfl_xor(ss, off);
    float r = rsqrtf(ss * (1.0f / 128.0f) + 1e-6f);
    const float* nw = (type == 0) ? qnw : knw;
    float n0 = e0 * r * nw[l], n1 = e1 * r * nw[l + 64];
    float c0 = cosb[s * 128 + l], c1 = cosb[s * 128 + 64 + l];
    float s0 = sinb[s * 128 + l], s1 = sinb[s * 128 + 64 + l];
    out0 = n0 * c0 - n1 * s0;
    out1 = n1 * c1 + n0 * s1;
  } else { out0 = e0; out1 = e1; }
  if (type == 0) {
    short* d = qb + (size_t)t * 4096 + h * 128;
    d[l] = f2bf(out0); d[l + 64] = f2bf(out1);
  } else {
    int br = idx[t];
    float* bd = bufo + (size_t)br * 2048 + (type == 1 ? 0 : 1024) + h * 128;
    bd[l] = out0; bd[l + 64] = out1;
    short* d = (type == 1) ? kbp + (size_t)t * 1024 + h * 128
                           : vbp + (size_t)t * 1024 + h * 128;
    d[l] = f2bf(out0); d[l + 64] = f2bf(out1);
  }
}

// ---------------- causal GQA flash attention ----------------
// block = (b, h, 64-q-row tile), 4 waves of 16 q rows each, KV tiles of 64
#define KLD 136
#define VLD 72
#define PLD 72

__global__ __launch_bounds__(256) void attn_k(const short* __restrict__ qb,
    const short* __restrict__ kbp, const short* __restrict__ vbp,
    short* __restrict__ ob) {
  __shared__ short Ks[64 * KLD];
  __shared__ short Vs[128 * VLD];
  __shared__ short Ps[4][16 * PLD];
  const int bid = blockIdx.x;
  const int qt = bid & 15, h = (bid >> 4) & 31, b = bid >> 9;
  const int kvh = h >> 2;
  const int tid = threadIdx.x, lane = tid & 63, w = tid >> 6;
  const int lrow = lane & 15, lg = lane >> 4, lk = lg << 3;
  const int q0 = qt << 6;
  const float SC2 = 0.088388347648318447f * 1.4426950408889634f; // scale*log2(e)

  bf16x8 qf[4];
  {
    const short* qp = qb + ((size_t)(b * 1024 + q0 + w * 16 + lrow) * 32 + h) * 128 + lk;
    #pragma unroll
    for (int kb4 = 0; kb4 < 4; ++kb4) qf[kb4] = ld8(qp + kb4 * 32);
  }
  float m[4], lsum[4];
  fx4 acc[8] = {};
  #pragma unroll
  for (int j = 0; j < 4; ++j) { m[j] = -3.0e38f; lsum[j] = 0.f; }

  for (int kt = 0; kt <= qt; ++kt) {
    const int kv0 = kt << 6;
    // stage K row-major + V transposed (XOR-swizzled kv index)
    #pragma unroll
    for (int it = 0; it < 4; ++it) {
      int idx = it * 256 + tid;
      int r = idx >> 4, d8 = (idx & 15) << 3;
      size_t base = ((size_t)(b * 1024 + kv0 + r) * 8 + kvh) * 128 + d8;
      *(s16x8*)&Ks[r * KLD + d8] = *(const s16x8*)(kbp + base);
      s16x8 vv = *(const s16x8*)(vbp + base);
      int swz = ((d8 >> 3) & 7) << 3;
      #pragma unroll
      for (int j = 0; j < 8; ++j)
        Vs[(d8 + j) * VLD + (r ^ swz)] = vv[j];
    }
    __syncthreads();
    // S = Q K^T (16x64 per wave)
    fx4 sf[4];
    #pragma unroll
    for (int nc = 0; nc < 4; ++nc) {
      fx4 z = {0.f, 0.f, 0.f, 0.f};
      sf[nc] = z;
      #pragma unroll
      for (int kb4 = 0; kb4 < 4; ++kb4) {
        bf16x8 kf = ld8(&Ks[(nc * 16 + lrow) * KLD + kb4 * 32 + lk]);
        sf[nc] = __builtin_amdgcn_mfma_f32_16x16x32_bf16(qf[kb4], kf, sf[nc], 0, 0, 0);
      }
    }
    // causal mask on the diagonal tile
    if (kt == qt) {
      #pragma unroll
      for (int nc = 0; nc < 4; ++nc)
        #pragma unroll
        for (int j = 0; j < 4; ++j) {
          int qr = q0 + w * 16 + (lg << 2) + j;
          int kc = kv0 + nc * 16 + lrow;
          if (kc > qr) sf[nc][j] = -3.0e38f;
        }
    }
    // online softmax (rows live in lanes sharing lg; reduce over low 4 lane bits)
    float pm[4];
    #pragma unroll
    for (int j = 0; j < 4; ++j) pm[j] = -3.0e38f;
    #pragma unroll
    for (int nc = 0; nc < 4; ++nc)
      #pragma unroll
      for (int j = 0; j < 4; ++j) pm[j] = fmaxf(pm[j], sf[nc][j]);
    #pragma unroll
    for (int j = 0; j < 4; ++j) {
      pm[j] = fmaxf(pm[j], __shfl_xor(pm[j], 1));
      pm[j] = fmaxf(pm[j], __shfl_xor(pm[j], 2));
      pm[j] = fmaxf(pm[j], __shfl_xor(pm[j], 4));
      pm[j] = fmaxf(pm[j], __shfl_xor(pm[j], 8));
    }
    float alpha[4], rs[4];
    #pragma unroll
    for (int j = 0; j < 4; ++j) {
      float mn = fmaxf(m[j], pm[j]);
      alpha[j] = exp2f((m[j] - mn) * SC2);
      m[j] = mn;
      rs[j] = 0.f;
    }
    #pragma unroll
    for (int nc = 0; nc < 4; ++nc)
      #pragma unroll
      for (int j = 0; j < 4; ++j) {
        float p = exp2f((sf[nc][j] - m[j]) * SC2);
        rs[j] += p;
        Ps[w][((lg << 2) + j) * PLD + nc * 16 + lrow] = f2bf(p);
      }
    #pragma unroll
    for (int j = 0; j < 4; ++j) {
      rs[j] += __shfl_xor(rs[j], 1);
      rs[j] += __shfl_xor(rs[j], 2);
      rs[j] += __shfl_xor(rs[j], 4);
      rs[j] += __shfl_xor(rs[j], 8);
      lsum[j] = lsum[j] * alpha[j] + rs[j];
    }
    #pragma unroll
    for (int dg = 0; dg < 8; ++dg)
      #pragma unroll
      for (int j = 0; j < 4; ++j) acc[dg][j] *= alpha[j];
    // PV
    #pragma unroll
    for (int kb2 = 0; kb2 < 2; ++kb2) {
      bf16x8 pf = ld8(&Ps[w][lrow * PLD + kb2 * 32 + lk]);
      #pragma unroll
      for (int dg = 0; dg < 8; ++dg) {
        int d = dg * 16 + lrow;
        int kvs = (kb2 * 32 + lk) ^ (((d >> 3) & 7) << 3);
        bf16x8 vf = ld8(&Vs[d * VLD + kvs]);
        acc[dg] = __builtin_amdgcn_mfma_f32_16x16x32_bf16(pf, vf, acc[dg], 0, 0, 0);
      }
    }
    __syncthreads();
  }
  // epilogue
  #pragma unroll
  for (int j = 0; j < 4; ++j) {
    float rl = 1.0f / lsum[j];
    int t = b * 1024 + q0 + w * 16 + (lg << 2) + j;
    short* op = ob + ((size_t)t * 32 + h) * 128;
    #pragma unroll
    for (int dg = 0; dg < 8; ++dg)
      op[dg * 16 + lrow] = f2bf(acc[dg][j] * rl);
  }
}

// ---------------- launcher ----------------
extern "C" void kernel_launch(void* const* d_in, const int* in_sizes, int n_in,
                              void* d_out, int out_size, void* d_ws, size_t ws_size,
                              hipStream_t stream) {
  (void)in_sizes; (void)n_in; (void)out_size; (void)ws_size;
  const float* x    = (const float*)d_in[0];
  const float* qw   = (const float*)d_in[1];
  const float* kvw  = (const float*)d_in[2];
  const float* ow   = (const float*)d_in[3];
  const float* qnw  = (const float*)d_in[4];
  const float* knw  = (const float*)d_in[5];
  const float* cosb = (const float*)d_in[6];
  const float* sinb = (const float*)d_in[7];
  const float* kvbf = (const float*)d_in[8];
  const int*   idx  = (const int*)d_in[9];

  float* outp = (float*)d_out;
  float* bufp = outp + (size_t)2048 * 4096;

  char* ws = (char*)d_ws;
  size_t off = 0;
  float* xq   = (float*)(ws + off); off += (size_t)2048 * 4096 * 4;  // f32 [2048][4096]
  float* xkv  = (float*)(ws + off); off += (size_t)2048 * 2048 * 4;  // f32 [2048][2048]
  short* qb   = (short*)(ws + off); off += (size_t)2048 * 4096 * 2;
  short* kbp  = (short*)(ws + off); off += (size_t)2048 * 1024 * 2;
  short* vbp  = (short*)(ws + off); off += (size_t)2048 * 1024 * 2;
  short* attnb = (short*)xkv;  // reuse (xkv dead after nr_k; 16.8 MB each)
  short* owt   = (short*)xq;   // reuse (xq dead after nr_k; 33.6 MB each)
  short* wt    = (short*)bufp; // buf region is scratch until the memcpy

  // 1) Q-proj: transpose qw into buf-scratch, then MFMA GEMM
  tr_k<<<dim3(64 * 64), dim3(256), 0, stream>>>(qw, wt, 4096, 4096);
  gemm_k<false><<<dim3(16 * 32), dim3(256), 0, stream>>>((const void*)x, wt, xq, 4096, 4096);
  // 2) KV-proj
  tr_k<<<dim3(64 * 32), dim3(256), 0, stream>>>(kvw, wt, 4096, 2048);
  gemm_k<false><<<dim3(16 * 16), dim3(256), 0, stream>>>((const void*)x, wt, xkv, 2048, 4096);
  // 3) kv buffer base copy (overwrites wt scratch), then norm/rope/scatter
  hipMemcpyAsync(bufp, kvbf, (size_t)16384 * 2048 * 4, hipMemcpyDeviceToDevice, stream);
  nr_k<<<dim3(98304 / 4), dim3(256), 0, stream>>>(xq, xkv, qnw, knw, cosb, sinb, idx,
                                                  qb, kbp, vbp, bufp);
  // 4) attention (writes attnb over dead xkv)
  attn_k<<<dim3(2 * 32 * 16), dim3(256), 0, stream>>>(qb, kbp, vbp, attnb);
  // 5) O-proj: transpose ow into dead xq, bf16-A GEMM
  tr_k<<<dim3(64 * 64), dim3(256), 0, stream>>>(ow, owt, 4096, 4096);
  gemm_k<true><<<dim3(16 * 32), dim3(256), 0, stream>>>((const void*)attnb, owt, outp, 4096, 4096);
}

// Round 4
// 473.736 us; speedup vs baseline: 1.4760x; 1.2883x over previous
//
#include <hip/hip_runtime.h>

// ---------------- common types/helpers ----------------
typedef float fx4 __attribute__((ext_vector_type(4)));
typedef short s16x4 __attribute__((ext_vector_type(4)));
typedef short s16x8 __attribute__((ext_vector_type(8)));
typedef __bf16 bf16x8 __attribute__((ext_vector_type(8)));

__device__ __forceinline__ short f2bf(float f) {
  unsigned u = __builtin_bit_cast(unsigned, f);
  u += 0x7fffu + ((u >> 16) & 1u);   // RNE
  return (short)(u >> 16);
}

__device__ __forceinline__ bf16x8 ld8(const short* p) {
  s16x8 v = *(const s16x8*)p;
  return __builtin_bit_cast(bf16x8, v);
}

// async global->LDS, 16B per lane; LDS dest is wave-uniform base + lane*16
__device__ __forceinline__ void gld16(const void* g, void* l) {
  __builtin_amdgcn_global_load_lds(
      (const __attribute__((address_space(1))) unsigned*)g,
      (__attribute__((address_space(3))) unsigned*)l, 16, 0, 0);
}

// ---------------- f32 -> bf16 convert (x pre-conversion) ----------------
__global__ __launch_bounds__(256) void cvt_k(const float* __restrict__ in,
                                             short* __restrict__ out) {
  int i = (blockIdx.x * 256 + threadIdx.x) * 8;
  fx4 a = *(const fx4*)(in + i);
  fx4 b = *(const fx4*)(in + i + 4);
  s16x8 w;
  w[0] = f2bf(a[0]); w[1] = f2bf(a[1]); w[2] = f2bf(a[2]); w[3] = f2bf(a[3]);
  w[4] = f2bf(b[0]); w[5] = f2bf(b[1]); w[6] = f2bf(b[2]); w[7] = f2bf(b[3]);
  *(s16x8*)(out + i) = w;
}

// ---------------- transpose+convert: out[n][k] = bf16(in[k][n]) ----------------
// in: f32 [K,N] row-major; out: bf16 [N,K]; 64x64 tiles, 256 threads
__global__ __launch_bounds__(256) void tr_k(const float* __restrict__ in,
    short* __restrict__ out, int K, int N) {
  __shared__ short T[64][72];
  const int ktiles = K >> 6;
  const int tk0 = (blockIdx.x % ktiles) << 6;
  const int tn0 = (blockIdx.x / ktiles) << 6;
  const int tid = threadIdx.x;
  #pragma unroll
  for (int i = 0; i < 4; ++i) {
    int idx = i * 256 + tid;
    int k = idx >> 4, n4 = (idx & 15) << 2;
    fx4 v = *(const fx4*)(in + (size_t)(tk0 + k) * N + tn0 + n4);
    #pragma unroll
    for (int j = 0; j < 4; ++j) T[n4 + j][k] = f2bf(v[j]);
  }
  __syncthreads();
  #pragma unroll
  for (int i = 0; i < 2; ++i) {
    int idx = i * 256 + tid;
    int n = idx >> 3, k8 = (idx & 7) << 3;
    *(s16x8*)(out + (size_t)(tn0 + n) * K + tk0 + k8) = *(const s16x8*)&T[n][k8];
  }
}

// ---------------- GEMM: C[M,N] = A[M,K] @ Bt[N,K]^T  (all bf16 in, f32 out) ----
// 128x128 tile, BK=64, 4 waves (2x2), 4x4 16x16x32 frags/wave, 32 MFMA/barrier.
// LDS tiles [128][64] bf16 LINEAR (global_load_lds); rows are 128B, so the
// 8 16B-chunks per row are XOR-permuted with (row&7) on the GLOBAL source and
// the same XOR is applied on ds_read -> 2-way (free) fragment reads.
__global__ __launch_bounds__(256) void gemm_k(const short* __restrict__ A,
    const short* __restrict__ Bt, float* __restrict__ Cp, int N, int K) {
  __shared__ short As[128 * 64];
  __shared__ short Bs[128 * 64];
  const int tiles_n = N >> 7;
  const int tm = blockIdx.x / tiles_n, tn = blockIdx.x % tiles_n;
  const int tid = threadIdx.x;
  const int lane = tid & 63, wv = tid >> 6;
  const int wr = (wv >> 1) << 6, wc = (wv & 1) << 6;
  const int r0 = tm << 7, c0 = tn << 7;
  const int lrow = lane & 15, lg = lane >> 4;
  const int srow = tid >> 3, sch = tid & 7;   // staging: 8 chunks per row
  fx4 acc[4][4] = {};

  for (int k0 = 0; k0 < K; k0 += 64) {
    // ---- stage A,B (128 x 64 each) via global_load_lds, source-swizzled ----
    #pragma unroll
    for (int i = 0; i < 4; ++i) {
      int row = (i << 5) + srow;                    // c = i*256+tid; row=c>>3
      int gk = ((sch ^ (row & 7)) << 3);
      gld16(A + (size_t)(r0 + row) * K + k0 + gk, &As[(i * 256 + wv * 64) * 8]);
    }
    #pragma unroll
    for (int i = 0; i < 4; ++i) {
      int row = (i << 5) + srow;
      int gk = ((sch ^ (row & 7)) << 3);
      gld16(Bt + (size_t)(c0 + row) * K + k0 + gk, &Bs[(i * 256 + wv * 64) * 8]);
    }
    __syncthreads();
    // ---- fragments (swizzled ds_read_b128) + MFMA ----
    bf16x8 af[4][2], bfr[4][2];
    #pragma unroll
    for (int m = 0; m < 4; ++m) {
      int row = wr + m * 16 + lrow;
      #pragma unroll
      for (int h = 0; h < 2; ++h)
        af[m][h] = ld8(&As[row * 64 + ((((h << 2) + lg) ^ (row & 7)) << 3)]);
    }
    #pragma unroll
    for (int n = 0; n < 4; ++n) {
      int row = wc + n * 16 + lrow;
      #pragma unroll
      for (int h = 0; h < 2; ++h)
        bfr[n][h] = ld8(&Bs[row * 64 + ((((h << 2) + lg) ^ (row & 7)) << 3)]);
    }
    #pragma unroll
    for (int m = 0; m < 4; ++m)
      #pragma unroll
      for (int n = 0; n < 4; ++n) {
        acc[m][n] = __builtin_amdgcn_mfma_f32_16x16x32_bf16(af[m][0], bfr[n][0], acc[m][n], 0, 0, 0);
        acc[m][n] = __builtin_amdgcn_mfma_f32_16x16x32_bf16(af[m][1], bfr[n][1], acc[m][n], 0, 0, 0);
      }
    __syncthreads();
  }
  // ---- epilogue: C layout col=lane&15, row=(lane>>4)*4+j ----
  const int g4 = lg << 2;
  #pragma unroll
  for (int m = 0; m < 4; ++m)
    #pragma unroll
    for (int n = 0; n < 4; ++n)
      #pragma unroll
      for (int j = 0; j < 4; ++j) {
        int row = r0 + wr + m * 16 + g4 + j;
        int col = c0 + wc + n * 16 + lrow;
        Cp[(size_t)row * N + col] = acc[m][n][j];
      }
}

// ---------------- RMSNorm + RoPE + KV scatter ----------------
// one wave per (token, head) row; lane l holds d=l and d=l+64 (rotate-half pairs)
// xqkv: f32 [2048][6144] — q at +0, k at +4096, v at +5120 (per token row)
__global__ __launch_bounds__(256) void nr_k(const float* __restrict__ xqkv,
    const float* __restrict__ qnw, const float* __restrict__ knw,
    const float* __restrict__ cosb, const float* __restrict__ sinb,
    const int* __restrict__ idx,
    short* __restrict__ qb, short* __restrict__ kbp, short* __restrict__ vbp,
    float* __restrict__ bufo) {
  int rid = blockIdx.x * 4 + (threadIdx.x >> 6);
  int l = threadIdx.x & 63;
  int type, t, h;
  if (rid < 65536)      { type = 0; t = rid >> 5; h = rid & 31; }
  else if (rid < 81920) { type = 1; int r = rid - 65536; t = r >> 3; h = r & 7; }
  else                  { type = 2; int r = rid - 81920; t = r >> 3; h = r & 7; }
  int s = t & 1023;
  const float* src = xqkv + (size_t)t * 6144 +
                     ((type == 0) ? h * 128 : (type == 1) ? 4096 + h * 128
                                                          : 5120 + h * 128);
  float e0 = src[l], e1 = src[l + 64];
  float out0, out1;
  if (type < 2) {
    float ss = e0 * e0 + e1 * e1;
    #pragma unroll
    for (int off = 1; off < 64; off <<= 1) ss += __shfl_xor(ss, off);
    float r = rsqrtf(ss * (1.0f / 128.0f) + 1e-6f);
    const float* nw = (type == 0) ? qnw : knw;
    float n0 = e0 * r * nw[l], n1 = e1 * r * nw[l + 64];
    float c0 = cosb[s * 128 + l], c1 = cosb[s * 128 + 64 + l];
    float s0 = sinb[s * 128 + l], s1 = sinb[s * 128 + 64 + l];
    out0 = n0 * c0 - n1 * s0;
    out1 = n1 * c1 + n0 * s1;
  } else { out0 = e0; out1 = e1; }
  if (type == 0) {
    short* d = qb + (size_t)t * 4096 + h * 128;
    d[l] = f2bf(out0); d[l + 64] = f2bf(out1);
  } else {
    int br = idx[t];
    float* bd = bufo + (size_t)br * 2048 + (type == 1 ? 0 : 1024) + h * 128;
    bd[l] = out0; bd[l + 64] = out1;
    short* d = (type == 1) ? kbp + (size_t)t * 1024 + h * 128
                           : vbp + (size_t)t * 1024 + h * 128;
    d[l] = f2bf(out0); d[l + 64] = f2bf(out1);
  }
}

// ---------------- causal GQA flash attention ----------------
// block = (b, h, 64-q-row tile), 4 waves of 16 q rows each, KV tiles of 64
#define KLD 136
#define VLD 72
#define PLD 72

__global__ __launch_bounds__(256) void attn_k(const short* __restrict__ qb,
    const short* __restrict__ kbp, const short* __restrict__ vbp,
    short* __restrict__ ob) {
  __shared__ short Ks[64 * KLD];
  __shared__ short Vs[128 * VLD];
  __shared__ short Ps[4][16 * PLD];
  const int bid = blockIdx.x;
  const int qt = bid & 15, h = (bid >> 4) & 31, b = bid >> 9;
  const int kvh = h >> 2;
  const int tid = threadIdx.x, lane = tid & 63, w = tid >> 6;
  const int lrow = lane & 15, lg = lane >> 4, lk = lg << 3;
  const int q0 = qt << 6;
  const float SC2 = 0.088388347648318447f * 1.4426950408889634f; // scale*log2(e)

  bf16x8 qf[4];
  {
    const short* qp = qb + ((size_t)(b * 1024 + q0 + w * 16 + lrow) * 32 + h) * 128 + lk;
    #pragma unroll
    for (int kb4 = 0; kb4 < 4; ++kb4) qf[kb4] = ld8(qp + kb4 * 32);
  }
  float m[4], lsum[4];
  fx4 acc[8] = {};
  #pragma unroll
  for (int j = 0; j < 4; ++j) { m[j] = -3.0e38f; lsum[j] = 0.f; }

  for (int kt = 0; kt <= qt; ++kt) {
    const int kv0 = kt << 6;
    // stage K row-major + V transposed (XOR-swizzled kv index)
    #pragma unroll
    for (int it = 0; it < 4; ++it) {
      int idx = it * 256 + tid;
      int r = idx >> 4, d8 = (idx & 15) << 3;
      size_t base = ((size_t)(b * 1024 + kv0 + r) * 8 + kvh) * 128 + d8;
      *(s16x8*)&Ks[r * KLD + d8] = *(const s16x8*)(kbp + base);
      s16x8 vv = *(const s16x8*)(vbp + base);
      int swz = ((d8 >> 3) & 7) << 3;
      #pragma unroll
      for (int j = 0; j < 8; ++j)
        Vs[(d8 + j) * VLD + (r ^ swz)] = vv[j];
    }
    __syncthreads();
    // S = Q K^T (16x64 per wave)
    fx4 sf[4];
    #pragma unroll
    for (int nc = 0; nc < 4; ++nc) {
      fx4 z = {0.f, 0.f, 0.f, 0.f};
      sf[nc] = z;
      #pragma unroll
      for (int kb4 = 0; kb4 < 4; ++kb4) {
        bf16x8 kf = ld8(&Ks[(nc * 16 + lrow) * KLD + kb4 * 32 + lk]);
        sf[nc] = __builtin_amdgcn_mfma_f32_16x16x32_bf16(qf[kb4], kf, sf[nc], 0, 0, 0);
      }
    }
    // causal mask on the diagonal tile
    if (kt == qt) {
      #pragma unroll
      for (int nc = 0; nc < 4; ++nc)
        #pragma unroll
        for (int j = 0; j < 4; ++j) {
          int qr = q0 + w * 16 + (lg << 2) + j;
          int kc = kv0 + nc * 16 + lrow;
          if (kc > qr) sf[nc][j] = -3.0e38f;
        }
    }
    // online softmax (rows live in lanes sharing lg; reduce over low 4 lane bits)
    float pm[4];
    #pragma unroll
    for (int j = 0; j < 4; ++j) pm[j] = -3.0e38f;
    #pragma unroll
    for (int nc = 0; nc < 4; ++nc)
      #pragma unroll
      for (int j = 0; j < 4; ++j) pm[j] = fmaxf(pm[j], sf[nc][j]);
    #pragma unroll
    for (int j = 0; j < 4; ++j) {
      pm[j] = fmaxf(pm[j], __shfl_xor(pm[j], 1));
      pm[j] = fmaxf(pm[j], __shfl_xor(pm[j], 2));
      pm[j] = fmaxf(pm[j], __shfl_xor(pm[j], 4));
      pm[j] = fmaxf(pm[j], __shfl_xor(pm[j], 8));
    }
    float alpha[4], rs[4];
    #pragma unroll
    for (int j = 0; j < 4; ++j) {
      float mn = fmaxf(m[j], pm[j]);
      alpha[j] = exp2f((m[j] - mn) * SC2);
      m[j] = mn;
      rs[j] = 0.f;
    }
    #pragma unroll
    for (int nc = 0; nc < 4; ++nc)
      #pragma unroll
      for (int j = 0; j < 4; ++j) {
        float p = exp2f((sf[nc][j] - m[j]) * SC2);
        rs[j] += p;
        Ps[w][((lg << 2) + j) * PLD + nc * 16 + lrow] = f2bf(p);
      }
    #pragma unroll
    for (int j = 0; j < 4; ++j) {
      rs[j] += __shfl_xor(rs[j], 1);
      rs[j] += __shfl_xor(rs[j], 2);
      rs[j] += __shfl_xor(rs[j], 4);
      rs[j] += __shfl_xor(rs[j], 8);
      lsum[j] = lsum[j] * alpha[j] + rs[j];
    }
    #pragma unroll
    for (int dg = 0; dg < 8; ++dg)
      #pragma unroll
      for (int j = 0; j < 4; ++j) acc[dg][j] *= alpha[j];
    // PV
    #pragma unroll
    for (int kb2 = 0; kb2 < 2; ++kb2) {
      bf16x8 pf = ld8(&Ps[w][lrow * PLD + kb2 * 32 + lk]);
      #pragma unroll
      for (int dg = 0; dg < 8; ++dg) {
        int d = dg * 16 + lrow;
        int kvs = (kb2 * 32 + lk) ^ (((d >> 3) & 7) << 3);
        bf16x8 vf = ld8(&Vs[d * VLD + kvs]);
        acc[dg] = __builtin_amdgcn_mfma_f32_16x16x32_bf16(pf, vf, acc[dg], 0, 0, 0);
      }
    }
    __syncthreads();
  }
  // epilogue
  #pragma unroll
  for (int j = 0; j < 4; ++j) {
    float rl = 1.0f / lsum[j];
    int t = b * 1024 + q0 + w * 16 + (lg << 2) + j;
    short* op = ob + ((size_t)t * 32 + h) * 128;
    #pragma unroll
    for (int dg = 0; dg < 8; ++dg)
      op[dg * 16 + lrow] = f2bf(acc[dg][j] * rl);
  }
}

// ---------------- launcher ----------------
extern "C" void kernel_launch(void* const* d_in, const int* in_sizes, int n_in,
                              void* d_out, int out_size, void* d_ws, size_t ws_size,
                              hipStream_t stream) {
  (void)in_sizes; (void)n_in; (void)out_size; (void)ws_size;
  const float* x    = (const float*)d_in[0];
  const float* qw   = (const float*)d_in[1];
  const float* kvw  = (const float*)d_in[2];
  const float* ow   = (const float*)d_in[3];
  const float* qnw  = (const float*)d_in[4];
  const float* knw  = (const float*)d_in[5];
  const float* cosb = (const float*)d_in[6];
  const float* sinb = (const float*)d_in[7];
  const float* kvbf = (const float*)d_in[8];
  const int*   idx  = (const int*)d_in[9];

  float* outp = (float*)d_out;
  float* bufp = outp + (size_t)2048 * 4096;   // 16384*2048 f32 = 134 MB

  // workspace (75.5 MB total, same footprint as the passing round)
  char* ws = (char*)d_ws;
  float* xqkv = (float*)ws;                                   // [2048][6144] f32, 50.3 MB
  short* qb   = (short*)(ws + (size_t)2048 * 6144 * 4);       // 16.8 MB
  short* kbp  = (short*)((char*)qb + (size_t)2048 * 4096 * 2); // 4.2 MB
  short* vbp  = (short*)((char*)kbp + (size_t)2048 * 1024 * 2);// 4.2 MB
  short* attnb = (short*)xqkv;                                // reuse after nr_k (16.8 MB)
  short* owt   = (short*)((char*)xqkv + (size_t)2048 * 4096 * 2); // reuse, 33.5 MB

  // scratch inside the (not-yet-written) kv_buffer output region:
  short* wqkvt = (short*)bufp;                                // [6144][4096] bf16, 50.3 MB
  short* xb    = (short*)((char*)bufp + (size_t)6144 * 4096 * 2); // [2048][4096] bf16, 16.8 MB

  // 1) pre-convert x to bf16; transpose fused [qw|kvw] -> bf16 [6144][4096]
  cvt_k<<<dim3(4096), dim3(256), 0, stream>>>(x, xb);
  tr_k<<<dim3(64 * 64), dim3(256), 0, stream>>>(qw, wqkvt, 4096, 4096);
  tr_k<<<dim3(64 * 32), dim3(256), 0, stream>>>(kvw, wqkvt + (size_t)4096 * 4096, 4096, 2048);
  // 2) fused QKV projection: [2048,4096] @ [4096,6144] -> [2048][6144]
  gemm_k<<<dim3(16 * 48), dim3(256), 0, stream>>>(xb, wqkvt, xqkv, 6144, 4096);
  // 3) kv buffer base copy (kills wqkvt/xb scratch), then norm/rope/scatter
  hipMemcpyAsync(bufp, kvbf, (size_t)16384 * 2048 * 4, hipMemcpyDeviceToDevice, stream);
  nr_k<<<dim3(98304 / 4), dim3(256), 0, stream>>>(xqkv, qnw, knw, cosb, sinb, idx,
                                                  qb, kbp, vbp, bufp);
  // 4) O-weight transpose into dead xqkv region; attention
  tr_k<<<dim3(64 * 64), dim3(256), 0, stream>>>(ow, owt, 4096, 4096);
  attn_k<<<dim3(2 * 32 * 16), dim3(256), 0, stream>>>(qb, kbp, vbp, attnb);
  // 5) O-proj
  gemm_k<<<dim3(16 * 32), dim3(256), 0, stream>>>(attnb, owt, outp, 4096, 4096);
}

// Round 5
// 441.910 us; speedup vs baseline: 1.5823x; 1.0720x over previous
//
#include <hip/hip_runtime.h>

// ---------------- common types/helpers ----------------
typedef float fx4 __attribute__((ext_vector_type(4)));
typedef short s16x4 __attribute__((ext_vector_type(4)));
typedef short s16x8 __attribute__((ext_vector_type(8)));
typedef __bf16 bf16x8 __attribute__((ext_vector_type(8)));

__device__ __forceinline__ short f2bf(float f) {
  unsigned u = __builtin_bit_cast(unsigned, f);
  u += 0x7fffu + ((u >> 16) & 1u);   // RNE
  return (short)(u >> 16);
}

__device__ __forceinline__ bf16x8 ld8(const short* p) {
  s16x8 v = *(const s16x8*)p;
  return __builtin_bit_cast(bf16x8, v);
}

// async global->LDS, 16B per lane; LDS dest is wave-uniform base + lane*16
__device__ __forceinline__ void gld16(const void* g, void* l) {
  __builtin_amdgcn_global_load_lds(
      (const __attribute__((address_space(1))) unsigned*)g,
      (__attribute__((address_space(3))) unsigned*)l, 16, 0, 0);
}

// ---------------- f32 -> bf16 convert (x pre-conversion) ----------------
__global__ __launch_bounds__(256) void cvt_k(const float* __restrict__ in,
                                             short* __restrict__ out) {
  int i = (blockIdx.x * 256 + threadIdx.x) * 8;
  fx4 a = *(const fx4*)(in + i);
  fx4 b = *(const fx4*)(in + i + 4);
  s16x8 w;
  w[0] = f2bf(a[0]); w[1] = f2bf(a[1]); w[2] = f2bf(a[2]); w[3] = f2bf(a[3]);
  w[4] = f2bf(b[0]); w[5] = f2bf(b[1]); w[6] = f2bf(b[2]); w[7] = f2bf(b[3]);
  *(s16x8*)(out + i) = w;
}

// ---------------- transpose+convert: out[n][k] = bf16(in[k][n]) ----------------
// in: f32 [K,N] row-major; out: bf16 [N,K]; 64x64 tiles, 256 threads
__global__ __launch_bounds__(256) void tr_k(const float* __restrict__ in,
    short* __restrict__ out, int K, int N) {
  __shared__ short T[64][72];
  const int ktiles = K >> 6;
  const int tk0 = (blockIdx.x % ktiles) << 6;
  const int tn0 = (blockIdx.x / ktiles) << 6;
  const int tid = threadIdx.x;
  #pragma unroll
  for (int i = 0; i < 4; ++i) {
    int idx = i * 256 + tid;
    int k = idx >> 4, n4 = (idx & 15) << 2;
    fx4 v = *(const fx4*)(in + (size_t)(tk0 + k) * N + tn0 + n4);
    #pragma unroll
    for (int j = 0; j < 4; ++j) T[n4 + j][k] = f2bf(v[j]);
  }
  __syncthreads();
  #pragma unroll
  for (int i = 0; i < 2; ++i) {
    int idx = i * 256 + tid;
    int n = idx >> 3, k8 = (idx & 7) << 3;
    *(s16x8*)(out + (size_t)(tn0 + n) * K + tk0 + k8) = *(const s16x8*)&T[n][k8];
  }
}

// ---------------- GEMM: C[M,N] = A[M,K] @ Bt[N,K]^T  (all bf16 in, f32 out) ----
// 128x128 tile, BK=64, 4 waves (2x2), 4x4 16x16x32 frags/wave, 32 MFMA/step.
// T3 2-phase double-buffered pipeline: stage tile t+1 via global_load_lds
// BEFORE computing tile t; ONE __syncthreads per K-step (its vmcnt(0) drain is
// what makes the swap safe). LDS tiles [128][64] LINEAR; 16B chunks XOR'd with
// (row&7) on the GLOBAL source and on ds_read (both-sides involution).
__global__ __launch_bounds__(256) void gemm_k(const short* __restrict__ A,
    const short* __restrict__ Bt, float* __restrict__ Cp, int N, int K) {
  __shared__ short As[2][128 * 64];
  __shared__ short Bs[2][128 * 64];
  const int tiles_n = N >> 7;
  const int tm = blockIdx.x / tiles_n, tn = blockIdx.x % tiles_n;
  const int tid = threadIdx.x;
  const int lane = tid & 63, wv = tid >> 6;
  const int wr = (wv >> 1) << 6, wc = (wv & 1) << 6;
  const int r0 = tm << 7, c0 = tn << 7;
  const int lrow = lane & 15, lg = lane >> 4;
  const int srow = tid >> 3, sch = tid & 7;   // staging: 8 chunks per row
  fx4 acc[4][4] = {};

  auto stage = [&](int buf, int k0) {
    #pragma unroll
    for (int i = 0; i < 4; ++i) {
      int row = (i << 5) + srow;
      int gk = ((sch ^ (row & 7)) << 3);
      gld16(A + (size_t)(r0 + row) * K + k0 + gk, &As[buf][(i * 256 + wv * 64) * 8]);
    }
    #pragma unroll
    for (int i = 0; i < 4; ++i) {
      int row = (i << 5) + srow;
      int gk = ((sch ^ (row & 7)) << 3);
      gld16(Bt + (size_t)(c0 + row) * K + k0 + gk, &Bs[buf][(i * 256 + wv * 64) * 8]);
    }
  };

  const int nt = K >> 6;
  stage(0, 0);
  __syncthreads();          // drain prologue loads
  int cur = 0;
  for (int t = 0; t < nt; ++t) {
    if (t + 1 < nt) stage(cur ^ 1, (t + 1) << 6);   // loads fly during compute
    bf16x8 af[4][2], bfr[4][2];
    #pragma unroll
    for (int m = 0; m < 4; ++m) {
      int row = wr + m * 16 + lrow;
      #pragma unroll
      for (int h = 0; h < 2; ++h)
        af[m][h] = ld8(&As[cur][row * 64 + ((((h << 2) + lg) ^ (row & 7)) << 3)]);
    }
    #pragma unroll
    for (int n = 0; n < 4; ++n) {
      int row = wc + n * 16 + lrow;
      #pragma unroll
      for (int h = 0; h < 2; ++h)
        bfr[n][h] = ld8(&Bs[cur][row * 64 + ((((h << 2) + lg) ^ (row & 7)) << 3)]);
    }
    __builtin_amdgcn_s_setprio(1);
    #pragma unroll
    for (int m = 0; m < 4; ++m)
      #pragma unroll
      for (int n = 0; n < 4; ++n) {
        acc[m][n] = __builtin_amdgcn_mfma_f32_16x16x32_bf16(af[m][0], bfr[n][0], acc[m][n], 0, 0, 0);
        acc[m][n] = __builtin_amdgcn_mfma_f32_16x16x32_bf16(af[m][1], bfr[n][1], acc[m][n], 0, 0, 0);
      }
    __builtin_amdgcn_s_setprio(0);
    __syncthreads();        // drains vmcnt(0)+lgkmcnt(0): next tile resident, swap safe
    cur ^= 1;
  }
  // ---- epilogue: C layout col=lane&15, row=(lane>>4)*4+j ----
  const int g4 = lg << 2;
  #pragma unroll
  for (int m = 0; m < 4; ++m)
    #pragma unroll
    for (int n = 0; n < 4; ++n)
      #pragma unroll
      for (int j = 0; j < 4; ++j) {
        int row = r0 + wr + m * 16 + g4 + j;
        int col = c0 + wc + n * 16 + lrow;
        Cp[(size_t)row * N + col] = acc[m][n][j];
      }
}

// ---------------- RMSNorm + RoPE + KV scatter ----------------
// one wave per (token, head) row; lane l holds d=l and d=l+64 (rotate-half pairs)
// xqkv: f32 [2048][6144] — q at +0, k at +4096, v at +5120 (per token row)
__global__ __launch_bounds__(256) void nr_k(const float* __restrict__ xqkv,
    const float* __restrict__ qnw, const float* __restrict__ knw,
    const float* __restrict__ cosb, const float* __restrict__ sinb,
    const int* __restrict__ idx,
    short* __restrict__ qb, short* __restrict__ kbp, short* __restrict__ vbp,
    float* __restrict__ bufo) {
  int rid = blockIdx.x * 4 + (threadIdx.x >> 6);
  int l = threadIdx.x & 63;
  int type, t, h;
  if (rid < 65536)      { type = 0; t = rid >> 5; h = rid & 31; }
  else if (rid < 81920) { type = 1; int r = rid - 65536; t = r >> 3; h = r & 7; }
  else                  { type = 2; int r = rid - 81920; t = r >> 3; h = r & 7; }
  int s = t & 1023;
  const float* src = xqkv + (size_t)t * 6144 +
                     ((type == 0) ? h * 128 : (type == 1) ? 4096 + h * 128
                                                          : 5120 + h * 128);
  float e0 = src[l], e1 = src[l + 64];
  float out0, out1;
  if (type < 2) {
    float ss = e0 * e0 + e1 * e1;
    #pragma unroll
    for (int off = 1; off < 64; off <<= 1) ss += __shfl_xor(ss, off);
    float r = rsqrtf(ss * (1.0f / 128.0f) + 1e-6f);
    const float* nw = (type == 0) ? qnw : knw;
    float n0 = e0 * r * nw[l], n1 = e1 * r * nw[l + 64];
    float c0 = cosb[s * 128 + l], c1 = cosb[s * 128 + 64 + l];
    float s0 = sinb[s * 128 + l], s1 = sinb[s * 128 + 64 + l];
    out0 = n0 * c0 - n1 * s0;
    out1 = n1 * c1 + n0 * s1;
  } else { out0 = e0; out1 = e1; }
  if (type == 0) {
    short* d = qb + (size_t)t * 4096 + h * 128;
    d[l] = f2bf(out0); d[l + 64] = f2bf(out1);
  } else {
    int br = idx[t];
    float* bd = bufo + (size_t)br * 2048 + (type == 1 ? 0 : 1024) + h * 128;
    bd[l] = out0; bd[l + 64] = out1;
    short* d = (type == 1) ? kbp + (size_t)t * 1024 + h * 128
                           : vbp + (size_t)t * 1024 + h * 128;
    d[l] = f2bf(out0); d[l + 64] = f2bf(out1);
  }
}

// ---------------- causal GQA flash attention ----------------
// block = (b, h, 64-q-row tile), 4 waves of 16 q rows each, KV tiles of 64
#define KLD 136
#define VLD 72
#define PLD 72

__global__ __launch_bounds__(256) void attn_k(const short* __restrict__ qb,
    const short* __restrict__ kbp, const short* __restrict__ vbp,
    short* __restrict__ ob) {
  __shared__ short Ks[64 * KLD];
  __shared__ short Vs[128 * VLD];
  __shared__ short Ps[4][16 * PLD];
  const int bid = blockIdx.x;
  const int qt = bid & 15, h = (bid >> 4) & 31, b = bid >> 9;
  const int kvh = h >> 2;
  const int tid = threadIdx.x, lane = tid & 63, w = tid >> 6;
  const int lrow = lane & 15, lg = lane >> 4, lk = lg << 3;
  const int q0 = qt << 6;
  const float SC2 = 0.088388347648318447f * 1.4426950408889634f; // scale*log2(e)

  bf16x8 qf[4];
  {
    const short* qp = qb + ((size_t)(b * 1024 + q0 + w * 16 + lrow) * 32 + h) * 128 + lk;
    #pragma unroll
    for (int kb4 = 0; kb4 < 4; ++kb4) qf[kb4] = ld8(qp + kb4 * 32);
  }
  float m[4], lsum[4];
  fx4 acc[8] = {};
  #pragma unroll
  for (int j = 0; j < 4; ++j) { m[j] = -3.0e38f; lsum[j] = 0.f; }

  for (int kt = 0; kt <= qt; ++kt) {
    const int kv0 = kt << 6;
    // stage K row-major + V transposed (XOR-swizzled kv index)
    #pragma unroll
    for (int it = 0; it < 4; ++it) {
      int idx = it * 256 + tid;
      int r = idx >> 4, d8 = (idx & 15) << 3;
      size_t base = ((size_t)(b * 1024 + kv0 + r) * 8 + kvh) * 128 + d8;
      *(s16x8*)&Ks[r * KLD + d8] = *(const s16x8*)(kbp + base);
      s16x8 vv = *(const s16x8*)(vbp + base);
      int swz = ((d8 >> 3) & 7) << 3;
      #pragma unroll
      for (int j = 0; j < 8; ++j)
        Vs[(d8 + j) * VLD + (r ^ swz)] = vv[j];
    }
    __syncthreads();
    // S = Q K^T (16x64 per wave)
    fx4 sf[4];
    #pragma unroll
    for (int nc = 0; nc < 4; ++nc) {
      fx4 z = {0.f, 0.f, 0.f, 0.f};
      sf[nc] = z;
      #pragma unroll
      for (int kb4 = 0; kb4 < 4; ++kb4) {
        bf16x8 kf = ld8(&Ks[(nc * 16 + lrow) * KLD + kb4 * 32 + lk]);
        sf[nc] = __builtin_amdgcn_mfma_f32_16x16x32_bf16(qf[kb4], kf, sf[nc], 0, 0, 0);
      }
    }
    // causal mask on the diagonal tile
    if (kt == qt) {
      #pragma unroll
      for (int nc = 0; nc < 4; ++nc)
        #pragma unroll
        for (int j = 0; j < 4; ++j) {
          int qr = q0 + w * 16 + (lg << 2) + j;
          int kc = kv0 + nc * 16 + lrow;
          if (kc > qr) sf[nc][j] = -3.0e38f;
        }
    }
    // online softmax (rows live in lanes sharing lg; reduce over low 4 lane bits)
    float pm[4];
    #pragma unroll
    for (int j = 0; j < 4; ++j) pm[j] = -3.0e38f;
    #pragma unroll
    for (int nc = 0; nc < 4; ++nc)
      #pragma unroll
      for (int j = 0; j < 4; ++j) pm[j] = fmaxf(pm[j], sf[nc][j]);
    #pragma unroll
    for (int j = 0; j < 4; ++j) {
      pm[j] = fmaxf(pm[j], __shfl_xor(pm[j], 1));
      pm[j] = fmaxf(pm[j], __shfl_xor(pm[j], 2));
      pm[j] = fmaxf(pm[j], __shfl_xor(pm[j], 4));
      pm[j] = fmaxf(pm[j], __shfl_xor(pm[j], 8));
    }
    float alpha[4], rs[4];
    #pragma unroll
    for (int j = 0; j < 4; ++j) {
      float mn = fmaxf(m[j], pm[j]);
      alpha[j] = exp2f((m[j] - mn) * SC2);
      m[j] = mn;
      rs[j] = 0.f;
    }
    #pragma unroll
    for (int nc = 0; nc < 4; ++nc)
      #pragma unroll
      for (int j = 0; j < 4; ++j) {
        float p = exp2f((sf[nc][j] - m[j]) * SC2);
        rs[j] += p;
        Ps[w][((lg << 2) + j) * PLD + nc * 16 + lrow] = f2bf(p);
      }
    #pragma unroll
    for (int j = 0; j < 4; ++j) {
      rs[j] += __shfl_xor(rs[j], 1);
      rs[j] += __shfl_xor(rs[j], 2);
      rs[j] += __shfl_xor(rs[j], 4);
      rs[j] += __shfl_xor(rs[j], 8);
      lsum[j] = lsum[j] * alpha[j] + rs[j];
    }
    #pragma unroll
    for (int dg = 0; dg < 8; ++dg)
      #pragma unroll
      for (int j = 0; j < 4; ++j) acc[dg][j] *= alpha[j];
    // PV
    #pragma unroll
    for (int kb2 = 0; kb2 < 2; ++kb2) {
      bf16x8 pf = ld8(&Ps[w][lrow * PLD + kb2 * 32 + lk]);
      #pragma unroll
      for (int dg = 0; dg < 8; ++dg) {
        int d = dg * 16 + lrow;
        int kvs = (kb2 * 32 + lk) ^ (((d >> 3) & 7) << 3);
        bf16x8 vf = ld8(&Vs[d * VLD + kvs]);
        acc[dg] = __builtin_amdgcn_mfma_f32_16x16x32_bf16(pf, vf, acc[dg], 0, 0, 0);
      }
    }
    __syncthreads();
  }
  // epilogue
  #pragma unroll
  for (int j = 0; j < 4; ++j) {
    float rl = 1.0f / lsum[j];
    int t = b * 1024 + q0 + w * 16 + (lg << 2) + j;
    short* op = ob + ((size_t)t * 32 + h) * 128;
    #pragma unroll
    for (int dg = 0; dg < 8; ++dg)
      op[dg * 16 + lrow] = f2bf(acc[dg][j] * rl);
  }
}

// ---------------- launcher ----------------
extern "C" void kernel_launch(void* const* d_in, const int* in_sizes, int n_in,
                              void* d_out, int out_size, void* d_ws, size_t ws_size,
                              hipStream_t stream) {
  (void)in_sizes; (void)n_in; (void)out_size; (void)ws_size;
  const float* x    = (const float*)d_in[0];
  const float* qw   = (const float*)d_in[1];
  const float* kvw  = (const float*)d_in[2];
  const float* ow   = (const float*)d_in[3];
  const float* qnw  = (const float*)d_in[4];
  const float* knw  = (const float*)d_in[5];
  const float* cosb = (const float*)d_in[6];
  const float* sinb = (const float*)d_in[7];
  const float* kvbf = (const float*)d_in[8];
  const int*   idx  = (const int*)d_in[9];

  float* outp = (float*)d_out;
  float* bufp = outp + (size_t)2048 * 4096;   // 16384*2048 f32 = 134 MB

  // workspace (75.5 MB total)
  char* ws = (char*)d_ws;
  float* xqkv = (float*)ws;                                   // [2048][6144] f32, 50.3 MB
  short* qb   = (short*)(ws + (size_t)2048 * 6144 * 4);       // 16.8 MB
  short* kbp  = (short*)((char*)qb + (size_t)2048 * 4096 * 2); // 4.2 MB
  short* vbp  = (short*)((char*)kbp + (size_t)2048 * 1024 * 2);// 4.2 MB
  short* attnb = (short*)xqkv;                                // reuse after nr_k (16.8 MB)
  short* owt   = (short*)((char*)xqkv + (size_t)2048 * 4096 * 2); // reuse, 33.5 MB

  // scratch inside the (not-yet-written) kv_buffer output region:
  short* wqkvt = (short*)bufp;                                // [6144][4096] bf16, 50.3 MB
  short* xb    = (short*)((char*)bufp + (size_t)6144 * 4096 * 2); // [2048][4096] bf16, 16.8 MB

  // 1) pre-convert x to bf16; transpose fused [qw|kvw] -> bf16 [6144][4096]
  cvt_k<<<dim3(4096), dim3(256), 0, stream>>>(x, xb);
  tr_k<<<dim3(64 * 64), dim3(256), 0, stream>>>(qw, wqkvt, 4096, 4096);
  tr_k<<<dim3(64 * 32), dim3(256), 0, stream>>>(kvw, wqkvt + (size_t)4096 * 4096, 4096, 2048);
  // 2) fused QKV projection: [2048,4096] @ [4096,6144] -> [2048][6144]
  gemm_k<<<dim3(16 * 48), dim3(256), 0, stream>>>(xb, wqkvt, xqkv, 6144, 4096);
  // 3) kv buffer base copy: rows 2048.. only (rows 0..2047 fully rewritten by
  //    the scatter since cur_select_index covers them); kills wqkvt/xb scratch
  hipMemcpyAsync(bufp + (size_t)2048 * 2048, kvbf + (size_t)2048 * 2048,
                 (size_t)(16384 - 2048) * 2048 * 4, hipMemcpyDeviceToDevice, stream);
  nr_k<<<dim3(98304 / 4), dim3(256), 0, stream>>>(xqkv, qnw, knw, cosb, sinb, idx,
                                                  qb, kbp, vbp, bufp);
  // 4) O-weight transpose into dead xqkv region; attention
  tr_k<<<dim3(64 * 64), dim3(256), 0, stream>>>(ow, owt, 4096, 4096);
  attn_k<<<dim3(2 * 32 * 16), dim3(256), 0, stream>>>(qb, kbp, vbp, attnb);
  // 5) O-proj
  gemm_k<<<dim3(16 * 32), dim3(256), 0, stream>>>(attnb, owt, outp, 4096, 4096);
}